// Round 1
// baseline (86.868 us; speedup 1.0000x reference)
//
#include <hip/hip_runtime.h>

// 4-qubit circuit simulator, one thread per sample.
// State: 16 complex amps in registers. Wire w <-> bit (3-w): idx = i0*8+i1*4+i2*2+i3.

__global__ __launch_bounds__(256) void qenc_kernel(
    const float* __restrict__ x,      // [B,4]
    const float* __restrict__ wgt,    // [2,4]
    float* __restrict__ out,          // [B,4]
    int B)
{
    int b = blockIdx.x * blockDim.x + threadIdx.x;
    if (b >= B) return;

    // ---- per-sample embedding angles ----
    float4 xv = reinterpret_cast<const float4*>(x)[b];
    float cx[4], sx[4];
    __sincosf(xv.x * 0.5f, &sx[0], &cx[0]);
    __sincosf(xv.y * 0.5f, &sx[1], &cx[1]);
    __sincosf(xv.z * 0.5f, &sx[2], &cx[2]);
    __sincosf(xv.w * 0.5f, &sx[3], &cx[3]);

    // ---- shared weight angles (broadcast load, L2-cached) ----
    float4 w0 = reinterpret_cast<const float4*>(wgt)[0];
    float4 w1 = reinterpret_cast<const float4*>(wgt)[1];
    float cw[8], sw[8];
    __sincosf(w0.x * 0.5f, &sw[0], &cw[0]);
    __sincosf(w0.y * 0.5f, &sw[1], &cw[1]);
    __sincosf(w0.z * 0.5f, &sw[2], &cw[2]);
    __sincosf(w0.w * 0.5f, &sw[3], &cw[3]);
    __sincosf(w1.x * 0.5f, &sw[4], &cw[4]);
    __sincosf(w1.y * 0.5f, &sw[5], &cw[5]);
    __sincosf(w1.z * 0.5f, &sw[6], &cw[6]);
    __sincosf(w1.w * 0.5f, &sw[7], &cw[7]);

    // ---- product state after AngleEmbedding: amp[i] = m(i) * (-i)^popc(i) ----
    // factor per wire: bit=0 -> cos, bit=1 -> (-i)*sin
    float sr[16], si[16];
#pragma unroll
    for (int i = 0; i < 16; ++i) {
        float m = ((i & 8) ? sx[0] : cx[0]);
        m *= ((i & 4) ? sx[1] : cx[1]);
        m *= ((i & 2) ? sx[2] : cx[2]);
        m *= ((i & 1) ? sx[3] : cx[3]);
        int k = __popc(i) & 3;
        // (-i)^k: 0->(1,0) 1->(0,-1) 2->(-1,0) 3->(0,1)  (folds to constants after unroll)
        sr[i] = (k == 0) ? m : ((k == 2) ? -m : 0.0f);
        si[i] = (k == 1) ? -m : ((k == 3) ? m : 0.0f);
    }

    // ---- 2 BasicEntangler layers: RX(w[l][q]) on each wire, then CNOT ring ----
#pragma unroll
    for (int l = 0; l < 2; ++l) {
        // RX gates
#pragma unroll
        for (int q = 0; q < 4; ++q) {
            float c = cw[l * 4 + q];
            float s = sw[l * 4 + q];
            int mask = 8 >> q;
#pragma unroll
            for (int i = 0; i < 16; ++i) {
                if (i & mask) continue;
                int j = i | mask;
                float a0r = sr[i], a0i = si[i];
                float a1r = sr[j], a1i = si[j];
                // new0 = c*a0 - i*s*a1 ; new1 = -i*s*a0 + c*a1
                sr[i] = c * a0r + s * a1i;
                si[i] = c * a0i - s * a1r;
                sr[j] = c * a1r + s * a0i;
                si[j] = c * a1i - s * a0r;
            }
        }
        // CNOT ring: (0,1),(1,2),(2,3),(3,0) sequentially
#pragma unroll
        for (int q = 0; q < 4; ++q) {
            int cm = 8 >> q;
            int tm = 8 >> ((q + 1) & 3);
#pragma unroll
            for (int i = 0; i < 16; ++i) {
                if ((i & cm) && !(i & tm)) {
                    int j = i | tm;
                    float tr = sr[i]; sr[i] = sr[j]; sr[j] = tr;
                    float ti = si[i]; si[i] = si[j]; si[j] = ti;
                }
            }
        }
    }

    // ---- expvals <Z_w> ----
    float e0 = 0.f, e1 = 0.f, e2 = 0.f, e3 = 0.f;
#pragma unroll
    for (int i = 0; i < 16; ++i) {
        float p = sr[i] * sr[i] + si[i] * si[i];
        e0 += (i & 8) ? -p : p;
        e1 += (i & 4) ? -p : p;
        e2 += (i & 2) ? -p : p;
        e3 += (i & 1) ? -p : p;
    }

    reinterpret_cast<float4*>(out)[b] = make_float4(e0, e1, e2, e3);
}

extern "C" void kernel_launch(void* const* d_in, const int* in_sizes, int n_in,
                              void* d_out, int out_size, void* d_ws, size_t ws_size,
                              hipStream_t stream) {
    const float* x   = (const float*)d_in[0];
    const float* wgt = (const float*)d_in[1];
    float* out = (float*)d_out;
    int B = in_sizes[0] / 4;
    int block = 256;
    int grid = (B + block - 1) / block;
    qenc_kernel<<<grid, block, 0, stream>>>(x, wgt, out, B);
}

// Round 2
// 86.505 us; speedup vs baseline: 1.0042x; 1.0042x over previous
//
#include <hip/hip_runtime.h>

// 4-qubit circuit simulator, one thread per sample.
// State: 16 complex amps in registers. Wire w <-> bit (3-w): idx = i0*8+i1*4+i2*2+i3.
// Round 2: replace precise __sincosf (ocml slow path, pointer outs) with
// native __sinf/__cosf -> v_sin_f32/v_cos_f32.

__global__ __launch_bounds__(256) void qenc_kernel(
    const float* __restrict__ x,      // [B,4]
    const float* __restrict__ wgt,    // [2,4]
    float* __restrict__ out,          // [B,4]
    int B)
{
    int b = blockIdx.x * blockDim.x + threadIdx.x;
    if (b >= B) return;

    // ---- per-sample embedding half-angles ----
    float4 xv = reinterpret_cast<const float4*>(x)[b];
    float cx[4], sx[4];
    {
        float h0 = xv.x * 0.5f, h1 = xv.y * 0.5f, h2 = xv.z * 0.5f, h3 = xv.w * 0.5f;
        sx[0] = __sinf(h0); cx[0] = __cosf(h0);
        sx[1] = __sinf(h1); cx[1] = __cosf(h1);
        sx[2] = __sinf(h2); cx[2] = __cosf(h2);
        sx[3] = __sinf(h3); cx[3] = __cosf(h3);
    }

    // ---- shared weight half-angles (uniform across threads, L2/L1 cached) ----
    float4 w0 = reinterpret_cast<const float4*>(wgt)[0];
    float4 w1 = reinterpret_cast<const float4*>(wgt)[1];
    float cw[8], sw[8];
    {
        float h;
        h = w0.x * 0.5f; sw[0] = __sinf(h); cw[0] = __cosf(h);
        h = w0.y * 0.5f; sw[1] = __sinf(h); cw[1] = __cosf(h);
        h = w0.z * 0.5f; sw[2] = __sinf(h); cw[2] = __cosf(h);
        h = w0.w * 0.5f; sw[3] = __sinf(h); cw[3] = __cosf(h);
        h = w1.x * 0.5f; sw[4] = __sinf(h); cw[4] = __cosf(h);
        h = w1.y * 0.5f; sw[5] = __sinf(h); cw[5] = __cosf(h);
        h = w1.z * 0.5f; sw[6] = __sinf(h); cw[6] = __cosf(h);
        h = w1.w * 0.5f; sw[7] = __sinf(h); cw[7] = __cosf(h);
    }

    // ---- product state after AngleEmbedding: amp[i] = m(i) * (-i)^popc(i) ----
    // factor per wire: bit=0 -> cos, bit=1 -> (-i)*sin
    float sr[16], si[16];
#pragma unroll
    for (int i = 0; i < 16; ++i) {
        float m = ((i & 8) ? sx[0] : cx[0]);
        m *= ((i & 4) ? sx[1] : cx[1]);
        m *= ((i & 2) ? sx[2] : cx[2]);
        m *= ((i & 1) ? sx[3] : cx[3]);
        int k = __popc(i) & 3;
        // (-i)^k: 0->(1,0) 1->(0,-1) 2->(-1,0) 3->(0,1)  (folds to constants after unroll)
        sr[i] = (k == 0) ? m : ((k == 2) ? -m : 0.0f);
        si[i] = (k == 1) ? -m : ((k == 3) ? m : 0.0f);
    }

    // ---- 2 BasicEntangler layers: RX(w[l][q]) on each wire, then CNOT ring ----
#pragma unroll
    for (int l = 0; l < 2; ++l) {
        // RX gates
#pragma unroll
        for (int q = 0; q < 4; ++q) {
            float c = cw[l * 4 + q];
            float s = sw[l * 4 + q];
            int mask = 8 >> q;
#pragma unroll
            for (int i = 0; i < 16; ++i) {
                if (i & mask) continue;
                int j = i | mask;
                float a0r = sr[i], a0i = si[i];
                float a1r = sr[j], a1i = si[j];
                // new0 = c*a0 - i*s*a1 ; new1 = -i*s*a0 + c*a1
                sr[i] = c * a0r + s * a1i;
                si[i] = c * a0i - s * a1r;
                sr[j] = c * a1r + s * a0i;
                si[j] = c * a1i - s * a0r;
            }
        }
        // CNOT ring: (0,1),(1,2),(2,3),(3,0) sequentially (register renames after unroll)
#pragma unroll
        for (int q = 0; q < 4; ++q) {
            int cm = 8 >> q;
            int tm = 8 >> ((q + 1) & 3);
#pragma unroll
            for (int i = 0; i < 16; ++i) {
                if ((i & cm) && !(i & tm)) {
                    int j = i | tm;
                    float tr = sr[i]; sr[i] = sr[j]; sr[j] = tr;
                    float ti = si[i]; si[i] = si[j]; si[j] = ti;
                }
            }
        }
    }

    // ---- expvals <Z_w> ----
    float e0 = 0.f, e1 = 0.f, e2 = 0.f, e3 = 0.f;
#pragma unroll
    for (int i = 0; i < 16; ++i) {
        float p = sr[i] * sr[i] + si[i] * si[i];
        e0 += (i & 8) ? -p : p;
        e1 += (i & 4) ? -p : p;
        e2 += (i & 2) ? -p : p;
        e3 += (i & 1) ? -p : p;
    }

    reinterpret_cast<float4*>(out)[b] = make_float4(e0, e1, e2, e3);
}

extern "C" void kernel_launch(void* const* d_in, const int* in_sizes, int n_in,
                              void* d_out, int out_size, void* d_ws, size_t ws_size,
                              hipStream_t stream) {
    const float* x   = (const float*)d_in[0];
    const float* wgt = (const float*)d_in[1];
    float* out = (float*)d_out;
    int B = in_sizes[0] / 4;
    int block = 256;
    int grid = (B + block - 1) / block;
    qenc_kernel<<<grid, block, 0, stream>>>(x, wgt, out, B);
}

// Round 3
// 80.416 us; speedup vs baseline: 1.0802x; 1.0757x over previous
//
#include <hip/hip_runtime.h>

// 4-qubit circuit simulator, one thread per sample, state = 16 complex amps
// held as float2 (re, im) in registers.
// Round 3: packed-fp32 formulation. RX pair update written as float2 math:
//   A0' = (c,c)*A0 + (s,-s)*swap(A1) ;  A1' = (c,c)*A1 + (s,-s)*swap(A0)
// so LLVM can select v_pk_mul_f32 / v_pk_fma_f32 (2x fp32 rate on gfx950).
// Product-state build shares sub-products (24 muls), expvals use packed
// sign-vector accumulation.

__device__ __forceinline__ float2 f2(float a, float b) { return make_float2(a, b); }

__global__ __launch_bounds__(256) void qenc_kernel(
    const float* __restrict__ x,      // [B,4]
    const float* __restrict__ wgt,    // [2,4]
    float* __restrict__ out,          // [B,4]
    int B)
{
    int b = blockIdx.x * blockDim.x + threadIdx.x;
    if (b >= B) return;

    // ---- per-sample embedding half-angle trig ----
    float4 xv = reinterpret_cast<const float4*>(x)[b];
    float cx[4], sx[4];
    {
        float h0 = xv.x * 0.5f, h1 = xv.y * 0.5f, h2 = xv.z * 0.5f, h3 = xv.w * 0.5f;
        sx[0] = __sinf(h0); cx[0] = __cosf(h0);
        sx[1] = __sinf(h1); cx[1] = __cosf(h1);
        sx[2] = __sinf(h2); cx[2] = __cosf(h2);
        sx[3] = __sinf(h3); cx[3] = __cosf(h3);
    }

    // ---- shared weight half-angle trig (wave-uniform values) ----
    float4 w0 = reinterpret_cast<const float4*>(wgt)[0];
    float4 w1 = reinterpret_cast<const float4*>(wgt)[1];
    float cw[8], sw[8];
    {
        float h;
        h = w0.x * 0.5f; sw[0] = __sinf(h); cw[0] = __cosf(h);
        h = w0.y * 0.5f; sw[1] = __sinf(h); cw[1] = __cosf(h);
        h = w0.z * 0.5f; sw[2] = __sinf(h); cw[2] = __cosf(h);
        h = w0.w * 0.5f; sw[3] = __sinf(h); cw[3] = __cosf(h);
        h = w1.x * 0.5f; sw[4] = __sinf(h); cw[4] = __cosf(h);
        h = w1.y * 0.5f; sw[5] = __sinf(h); cw[5] = __cosf(h);
        h = w1.z * 0.5f; sw[6] = __sinf(h); cw[6] = __cosf(h);
        h = w1.w * 0.5f; sw[7] = __sinf(h); cw[7] = __cosf(h);
    }

    // ---- product state after AngleEmbedding via shared sub-products ----
    // idx bit (3-w) <-> wire w. factor: bit=0 -> cos, bit=1 -> (-i)*sin
    // amp[i] = m(i) * (-i)^popc(i),  m(i) = p01[i>>2] * p23[i&3]
    float p01[4], p23[4];
    p01[0] = cx[0] * cx[1]; p01[1] = cx[0] * sx[1];
    p01[2] = sx[0] * cx[1]; p01[3] = sx[0] * sx[1];
    p23[0] = cx[2] * cx[3]; p23[1] = cx[2] * sx[3];
    p23[2] = sx[2] * cx[3]; p23[3] = sx[2] * sx[3];

    float2 st[16];
#pragma unroll
    for (int i = 0; i < 16; ++i) {
        float m = p01[i >> 2] * p23[i & 3];
        int k = __popc(i) & 3;
        // (-i)^k: 0->(1,0) 1->(0,-1) 2->(-1,0) 3->(0,1)
        st[i] = (k == 0) ? f2(m, 0.f)
              : (k == 1) ? f2(0.f, -m)
              : (k == 2) ? f2(-m, 0.f)
              :            f2(0.f, m);
    }

    // ---- 2 BasicEntangler layers: RX on each wire, then CNOT ring ----
#pragma unroll
    for (int l = 0; l < 2; ++l) {
#pragma unroll
        for (int q = 0; q < 4; ++q) {
            float c = cw[l * 4 + q];
            float s = sw[l * 4 + q];
            float2 cc = f2(c, c);
            float2 sn = f2(s, -s);
            int mask = 8 >> q;
#pragma unroll
            for (int i = 0; i < 16; ++i) {
                if (i & mask) continue;
                int j = i | mask;
                float2 A0 = st[i], A1 = st[j];
                float2 A0s = f2(A0.y, A0.x);
                float2 A1s = f2(A1.y, A1.x);
                // new0 = c*A0 + s*(-i)*A1 ; new1 = c*A1 + s*(-i)*A0
                st[i] = f2(cc.x * A0.x + sn.x * A1s.x, cc.y * A0.y + sn.y * A1s.y);
                st[j] = f2(cc.x * A1.x + sn.x * A0s.x, cc.y * A1.y + sn.y * A0s.y);
            }
        }
        // CNOT ring (register renames after unroll)
#pragma unroll
        for (int q = 0; q < 4; ++q) {
            int cm = 8 >> q;
            int tm = 8 >> ((q + 1) & 3);
#pragma unroll
            for (int i = 0; i < 16; ++i) {
                if ((i & cm) && !(i & tm)) {
                    int j = i | tm;
                    float2 t = st[i]; st[i] = st[j]; st[j] = t;
                }
            }
        }
    }

    // ---- expvals <Z_w>: packed sign-vector accumulation ----
    float2 e01 = f2(0.f, 0.f), e23 = f2(0.f, 0.f);
#pragma unroll
    for (int i = 0; i < 16; ++i) {
        float2 a = st[i];
        float p = a.x * a.x + a.y * a.y;
        float s0 = (i & 8) ? -1.f : 1.f;
        float s1 = (i & 4) ? -1.f : 1.f;
        float s2 = (i & 2) ? -1.f : 1.f;
        float s3 = (i & 1) ? -1.f : 1.f;
        e01 = f2(e01.x + s0 * p, e01.y + s1 * p);
        e23 = f2(e23.x + s2 * p, e23.y + s3 * p);
    }

    reinterpret_cast<float4*>(out)[b] = make_float4(e01.x, e01.y, e23.x, e23.y);
}

extern "C" void kernel_launch(void* const* d_in, const int* in_sizes, int n_in,
                              void* d_out, int out_size, void* d_ws, size_t ws_size,
                              hipStream_t stream) {
    const float* x   = (const float*)d_in[0];
    const float* wgt = (const float*)d_in[1];
    float* out = (float*)d_out;
    int B = in_sizes[0] / 4;
    int block = 256;
    int grid = (B + block - 1) / block;
    qenc_kernel<<<grid, block, 0, stream>>>(x, wgt, out, B);
}

// Round 4
// 78.071 us; speedup vs baseline: 1.1127x; 1.0300x over previous
//
#include <hip/hip_runtime.h>

// 4-qubit circuit simulator, one thread per sample, state = 16 complex amps
// (float2 re/im) in registers.
// Round 4: fuse AngleEmbedding RX(x_i) with layer-1 RX(w0_i) on the same wire
// (consecutive same-axis rotations: RX(a)RX(b)=RX(a+b)) -> layer-1 gate layer
// (128 packed instrs + 8 trans) collapses into 4 adds before the trig.
// Remaining circuit: product state -> CNOT ring -> RX(w1) layer -> CNOT ring
// -> <Z_w>. CNOT rings are compile-time register permutations (free).

__device__ __forceinline__ float2 f2(float a, float b) { return make_float2(a, b); }

__global__ __launch_bounds__(256) void qenc_kernel(
    const float* __restrict__ x,      // [B,4]
    const float* __restrict__ wgt,    // [2,4]
    float* __restrict__ out,          // [B,4]
    int B)
{
    int b = blockIdx.x * blockDim.x + threadIdx.x;
    if (b >= B) return;

    float4 xv = reinterpret_cast<const float4*>(x)[b];
    float4 w0 = reinterpret_cast<const float4*>(wgt)[0];
    float4 w1 = reinterpret_cast<const float4*>(wgt)[1];

    // ---- merged half-angles: RX(x_i)·RX(w0_i) = RX(x_i + w0_i) ----
    float cx[4], sx[4];
    {
        float h0 = (xv.x + w0.x) * 0.5f;
        float h1 = (xv.y + w0.y) * 0.5f;
        float h2 = (xv.z + w0.z) * 0.5f;
        float h3 = (xv.w + w0.w) * 0.5f;
        sx[0] = __sinf(h0); cx[0] = __cosf(h0);
        sx[1] = __sinf(h1); cx[1] = __cosf(h1);
        sx[2] = __sinf(h2); cx[2] = __cosf(h2);
        sx[3] = __sinf(h3); cx[3] = __cosf(h3);
    }

    // ---- layer-2 weight half-angle trig (wave-uniform) ----
    float cw[4], sw[4];
    {
        float h;
        h = w1.x * 0.5f; sw[0] = __sinf(h); cw[0] = __cosf(h);
        h = w1.y * 0.5f; sw[1] = __sinf(h); cw[1] = __cosf(h);
        h = w1.z * 0.5f; sw[2] = __sinf(h); cw[2] = __cosf(h);
        h = w1.w * 0.5f; sw[3] = __sinf(h); cw[3] = __cosf(h);
    }

    // ---- product state after merged RX layer ----
    // idx bit (3-w) <-> wire w. factor: bit=0 -> cos, bit=1 -> (-i)*sin
    // amp[i] = m(i) * (-i)^popc(i),  m(i) = p01[i>>2] * p23[i&3]
    float p01[4], p23[4];
    p01[0] = cx[0] * cx[1]; p01[1] = cx[0] * sx[1];
    p01[2] = sx[0] * cx[1]; p01[3] = sx[0] * sx[1];
    p23[0] = cx[2] * cx[3]; p23[1] = cx[2] * sx[3];
    p23[2] = sx[2] * cx[3]; p23[3] = sx[2] * sx[3];

    float2 st[16];
#pragma unroll
    for (int i = 0; i < 16; ++i) {
        float m = p01[i >> 2] * p23[i & 3];
        int k = __popc(i) & 3;
        // (-i)^k: 0->(1,0) 1->(0,-1) 2->(-1,0) 3->(0,1)
        st[i] = (k == 0) ? f2(m, 0.f)
              : (k == 1) ? f2(0.f, -m)
              : (k == 2) ? f2(-m, 0.f)
              :            f2(0.f, m);
    }

    // ---- CNOT ring #1: (0,1),(1,2),(2,3),(3,0) — register permutation ----
#pragma unroll
    for (int q = 0; q < 4; ++q) {
        int cm = 8 >> q;
        int tm = 8 >> ((q + 1) & 3);
#pragma unroll
        for (int i = 0; i < 16; ++i) {
            if ((i & cm) && !(i & tm)) {
                int j = i | tm;
                float2 t = st[i]; st[i] = st[j]; st[j] = t;
            }
        }
    }

    // ---- RX(w1_q) layer (the only remaining gate layer) ----
#pragma unroll
    for (int q = 0; q < 4; ++q) {
        float c = cw[q];
        float s = sw[q];
        int mask = 8 >> q;
#pragma unroll
        for (int i = 0; i < 16; ++i) {
            if (i & mask) continue;
            int j = i | mask;
            float2 A0 = st[i], A1 = st[j];
            // new0 = c*A0 + s*(-i)*A1 ; new1 = c*A1 + s*(-i)*A0
            // componentwise: re' = c*re + s*other.im ; im' = c*im - s*other.re
            st[i] = f2(c * A0.x + s * A1.y, c * A0.y - s * A1.x);
            st[j] = f2(c * A1.x + s * A0.y, c * A1.y - s * A0.x);
        }
    }

    // ---- CNOT ring #2 — register permutation ----
#pragma unroll
    for (int q = 0; q < 4; ++q) {
        int cm = 8 >> q;
        int tm = 8 >> ((q + 1) & 3);
#pragma unroll
        for (int i = 0; i < 16; ++i) {
            if ((i & cm) && !(i & tm)) {
                int j = i | tm;
                float2 t = st[i]; st[i] = st[j]; st[j] = t;
            }
        }
    }

    // ---- expvals <Z_w> ----
    float2 e01 = f2(0.f, 0.f), e23 = f2(0.f, 0.f);
#pragma unroll
    for (int i = 0; i < 16; ++i) {
        float2 a = st[i];
        float p = a.x * a.x + a.y * a.y;
        float s0 = (i & 8) ? -1.f : 1.f;
        float s1 = (i & 4) ? -1.f : 1.f;
        float s2 = (i & 2) ? -1.f : 1.f;
        float s3 = (i & 1) ? -1.f : 1.f;
        e01 = f2(e01.x + s0 * p, e01.y + s1 * p);
        e23 = f2(e23.x + s2 * p, e23.y + s3 * p);
    }

    reinterpret_cast<float4*>(out)[b] = make_float4(e01.x, e01.y, e23.x, e23.y);
}

extern "C" void kernel_launch(void* const* d_in, const int* in_sizes, int n_in,
                              void* d_out, int out_size, void* d_ws, size_t ws_size,
                              hipStream_t stream) {
    const float* x   = (const float*)d_in[0];
    const float* wgt = (const float*)d_in[1];
    float* out = (float*)d_out;
    int B = in_sizes[0] / 4;
    int block = 256;
    int grid = (B + block - 1) / block;
    qenc_kernel<<<grid, block, 0, stream>>>(x, wgt, out, B);
}

// Round 7
// 68.707 us; speedup vs baseline: 1.2643x; 1.1363x over previous
//
#include <hip/hip_runtime.h>

// Round 5 (2nd resubmit after GPU-acquisition timeouts): closed-form
// (Heisenberg-picture) evaluation. The 4-qubit circuit
//   RX(x_q + w0_q) product state -> CNOT ring -> RX(w1_q) -> CNOT ring -> <Z_w>
// collapses algebraically: conjugate Z_w back through the rings (Pauli string
// map) and the RX layer (Z -> cZ + sY); expectation on the product state kills
// every X-containing string (<X>=0) and leaves a tiny trig polynomial.
//   c_q = cos(w1_q), s_q = sin(w1_q); C_q = cos(x_q+w0_q), S_q = sin(x_q+w0_q)
//   E0 = C1C3(c1c2c3*C0 + s1s2s3*S0) + S1S3(s1s2c3*C0 + c1c2s3*S0)
//   E1 = c0c1*C0C2C3 + s0s1*S0S2C3
//   E2 = c0c1c2*C1C3 + c0s1s2*S1S3
//   E3 = C2(c0c1c2c3*C0 + c0s1s2s3*S0) + S2(s0c1s2s3*C0 + s0s1c2c3*S0)
// Verified against the state-vector simulation on 5 analytic special cases.
// ~55 VALU + 16 trans per thread -> memory-bound (16B in + 16B out per lane).

__global__ __launch_bounds__(256) void qenc_kernel(
    const float* __restrict__ x,      // [B,4]
    const float* __restrict__ wgt,    // [2,4]
    float* __restrict__ out,          // [B,4]
    int B)
{
    int b = blockIdx.x * blockDim.x + threadIdx.x;
    if (b >= B) return;

    float4 xv = reinterpret_cast<const float4*>(x)[b];
    float4 w0 = reinterpret_cast<const float4*>(wgt)[0];   // uniform -> s_load
    float4 w1 = reinterpret_cast<const float4*>(wgt)[1];

    // per-sample full angles and trig
    float a0 = xv.x + w0.x, a1 = xv.y + w0.y, a2 = xv.z + w0.z, a3 = xv.w + w0.w;
    float C0 = __cosf(a0), S0 = __sinf(a0);
    float C1 = __cosf(a1), S1 = __sinf(a1);
    float C2 = __cosf(a2), S2 = __sinf(a2);
    float C3 = __cosf(a3), S3 = __sinf(a3);

    // wave-uniform layer-2 trig (full angles)
    float c0 = __cosf(w1.x), s0 = __sinf(w1.x);
    float c1 = __cosf(w1.y), s1 = __sinf(w1.y);
    float c2 = __cosf(w1.z), s2 = __sinf(w1.z);
    float c3 = __cosf(w1.w), s3 = __sinf(w1.w);

    // uniform coefficient products
    float c1c2 = c1 * c2, s1s2 = s1 * s2;
    float k1 = c1c2 * c3;          // c1c2c3
    float k2 = c1c2 * s3;          // c1c2s3
    float k3 = s1s2 * c3;          // s1s2c3
    float k4 = s1s2 * s3;          // s1s2s3
    float k5 = c0 * c1;            // c0c1
    float k6 = s0 * s1;            // s0s1
    float k7 = c0 * c1c2;          // c0c1c2
    float k8 = c0 * s1s2;          // c0s1s2
    float k9 = k7 * c3;            // c0c1c2c3
    float k10 = k8 * s3;           // c0s1s2s3
    float k11 = (s0 * c1) * (s2 * s3); // s0c1s2s3
    float k12 = k6 * (c2 * c3);    // s0s1c2c3

    // per-sample pair products
    float C1C3 = C1 * C3, S1S3 = S1 * S3;
    float C2C3 = C2 * C3, S2C3 = S2 * C3;

    float E0 = C1C3 * (k1 * C0 + k4 * S0) + S1S3 * (k3 * C0 + k2 * S0);
    float E1 = k5 * (C0 * C2C3) + k6 * (S0 * S2C3);
    float E2 = k7 * C1C3 + k8 * S1S3;
    float E3 = C2 * (k9 * C0 + k10 * S0) + S2 * (k11 * C0 + k12 * S0);

    reinterpret_cast<float4*>(out)[b] = make_float4(E0, E1, E2, E3);
}

extern "C" void kernel_launch(void* const* d_in, const int* in_sizes, int n_in,
                              void* d_out, int out_size, void* d_ws, size_t ws_size,
                              hipStream_t stream) {
    const float* x   = (const float*)d_in[0];
    const float* wgt = (const float*)d_in[1];
    float* out = (float*)d_out;
    int B = in_sizes[0] / 4;
    int block = 256;
    int grid = (B + block - 1) / block;
    qenc_kernel<<<grid, block, 0, stream>>>(x, wgt, out, B);
}